// Round 1
// baseline (1324.120 us; speedup 1.0000x reference)
//
#include <hip/hip_runtime.h>
#include <math.h>

#define E_DIM 1024
#define H_DIM 16
#define D_DIM 64
#define B_DIM 2
#define T_DIM 2048

// ---------------------------------------------------------------------------
// bsum[e] = sum_h gate[h] * bo[h,e]
// ---------------------------------------------------------------------------
__global__ void bias_sum_kernel(const float* __restrict__ bo,
                                const float* __restrict__ gate,
                                float* __restrict__ bsum) {
    int e = blockIdx.x * blockDim.x + threadIdx.x;
    if (e < E_DIM) {
        float s = 0.f;
        #pragma unroll
        for (int h = 0; h < H_DIM; ++h) s += gate[h] * bo[h * E_DIM + e];
        bsum[e] = s;
    }
}

// ---------------------------------------------------------------------------
// Per-head projection GEMM: Out[b,h,t,d] = sum_e X[b,t,e]*W[h,e,d] + bias[h,d]
// Tile 64(m) x 64(n=d) x 16(k). Block = 256 threads, each 4x4 outputs.
// grid = (M/64, H)
// ---------------------------------------------------------------------------
__global__ __launch_bounds__(256) void proj_gemm_kernel(
    const float* __restrict__ X, const float* __restrict__ W,
    const float* __restrict__ bias, float* __restrict__ Out) {
    const int h = blockIdx.y;
    const int m0 = blockIdx.x * 64;      // global row m = b*T + t
    const int b = m0 / T_DIM;
    const int t0 = m0 % T_DIM;

    __shared__ float Xs[16][65];   // [kk][m], padded
    __shared__ float Ws[16][64];   // [kk][n]

    const int tid = threadIdx.x;
    const int tx = tid % 16, ty = tid / 16;

    float acc[4][4] = {};
    const float* Wh = W + (size_t)h * E_DIM * D_DIM;

    for (int k0 = 0; k0 < E_DIM; k0 += 16) {
        {   // X tile: 64 rows x 16 k
            int mm = tid / 4;
            int kk = (tid % 4) * 4;
            const float4 v = *reinterpret_cast<const float4*>(
                X + (size_t)(m0 + mm) * E_DIM + k0 + kk);
            Xs[kk + 0][mm] = v.x; Xs[kk + 1][mm] = v.y;
            Xs[kk + 2][mm] = v.z; Xs[kk + 3][mm] = v.w;
        }
        {   // W tile: 16 k x 64 n (contiguous in d)
            int kk = tid / 16;
            int n = (tid % 16) * 4;
            const float4 v = *reinterpret_cast<const float4*>(
                Wh + (size_t)(k0 + kk) * D_DIM + n);
            *reinterpret_cast<float4*>(&Ws[kk][n]) = v;
        }
        __syncthreads();
        #pragma unroll
        for (int kk = 0; kk < 16; ++kk) {
            float a[4], bb[4];
            #pragma unroll
            for (int i = 0; i < 4; ++i) a[i] = Xs[kk][ty * 4 + i];
            #pragma unroll
            for (int j = 0; j < 4; ++j) bb[j] = Ws[kk][tx * 4 + j];
            #pragma unroll
            for (int i = 0; i < 4; ++i)
                #pragma unroll
                for (int j = 0; j < 4; ++j)
                    acc[i][j] += a[i] * bb[j];
        }
        __syncthreads();
    }

    const float* bh = bias + h * D_DIM;
    float bj[4];
    #pragma unroll
    for (int j = 0; j < 4; ++j) bj[j] = bh[tx * 4 + j];
    float* Oh = Out + (size_t)(b * H_DIM + h) * T_DIM * D_DIM;
    #pragma unroll
    for (int i = 0; i < 4; ++i) {
        int t = t0 + ty * 4 + i;
        #pragma unroll
        for (int j = 0; j < 4; ++j)
            Oh[(size_t)t * D_DIM + tx * 4 + j] = acc[i][j] + bj[j];
    }
}

// ---------------------------------------------------------------------------
// Flash-style attention, fp32. One block per (b*H, q-tile of 64 rows).
// Online softmax; K-tile LDS buffer reused for P after S is computed.
// ---------------------------------------------------------------------------
__global__ __launch_bounds__(256) void attn_kernel(
    const float* __restrict__ Q, const float* __restrict__ K,
    const float* __restrict__ V, float* __restrict__ A) {
    const int bh = blockIdx.y;
    const int q0 = blockIdx.x * 64;
    const size_t base = (size_t)bh * T_DIM * D_DIM;

    __shared__ float Qs[64][65];
    __shared__ float KPs[64][65];   // K tile, then P tile
    __shared__ float Vs[64][65];

    const int tid = threadIdx.x;
    const int tx = tid % 16, ty = tid / 16;

    // load Q tile (64x64)
    #pragma unroll
    for (int i = 0; i < 4; ++i) {
        int r = tid / 16 + i * 16;
        int d0 = (tid % 16) * 4;
        float4 v = *reinterpret_cast<const float4*>(
            Q + base + (size_t)(q0 + r) * D_DIM + d0);
        Qs[r][d0 + 0] = v.x; Qs[r][d0 + 1] = v.y;
        Qs[r][d0 + 2] = v.z; Qs[r][d0 + 3] = v.w;
    }

    float m[4], l[4], O[4][4] = {};
    #pragma unroll
    for (int i = 0; i < 4; ++i) { m[i] = -INFINITY; l[i] = 0.f; }

    const float scale = 0.125f;   // 1/sqrt(64)

    for (int s0 = 0; s0 < T_DIM; s0 += 64) {
        // load K,V tiles
        #pragma unroll
        for (int i = 0; i < 4; ++i) {
            int r = tid / 16 + i * 16;
            int d0 = (tid % 16) * 4;
            float4 kv = *reinterpret_cast<const float4*>(
                K + base + (size_t)(s0 + r) * D_DIM + d0);
            KPs[r][d0 + 0] = kv.x; KPs[r][d0 + 1] = kv.y;
            KPs[r][d0 + 2] = kv.z; KPs[r][d0 + 3] = kv.w;
            float4 vv = *reinterpret_cast<const float4*>(
                V + base + (size_t)(s0 + r) * D_DIM + d0);
            Vs[r][d0 + 0] = vv.x; Vs[r][d0 + 1] = vv.y;
            Vs[r][d0 + 2] = vv.z; Vs[r][d0 + 3] = vv.w;
        }
        __syncthreads();

        // S = Q K^T * scale; thread owns rows ty*4.. cols tx*4..
        float S[4][4] = {};
        #pragma unroll
        for (int d = 0; d < 64; ++d) {
            float a[4], kk[4];
            #pragma unroll
            for (int i = 0; i < 4; ++i) a[i] = Qs[ty * 4 + i][d];
            #pragma unroll
            for (int j = 0; j < 4; ++j) kk[j] = KPs[tx * 4 + j][d];
            #pragma unroll
            for (int i = 0; i < 4; ++i)
                #pragma unroll
                for (int j = 0; j < 4; ++j)
                    S[i][j] += a[i] * kk[j];
        }
        #pragma unroll
        for (int i = 0; i < 4; ++i)
            #pragma unroll
            for (int j = 0; j < 4; ++j) S[i][j] *= scale;

        // online softmax (rows shared by the 16 lanes with equal ty;
        // tid = ty*16+tx so those are 16 contiguous lanes within a wave)
        #pragma unroll
        for (int i = 0; i < 4; ++i) {
            float mx = fmaxf(fmaxf(S[i][0], S[i][1]), fmaxf(S[i][2], S[i][3]));
            #pragma unroll
            for (int off = 1; off < 16; off <<= 1)
                mx = fmaxf(mx, __shfl_xor(mx, off));
            float newm = fmaxf(m[i], mx);
            float alpha = __expf(m[i] - newm);
            m[i] = newm;
            float s4 = 0.f;
            #pragma unroll
            for (int j = 0; j < 4; ++j) {
                S[i][j] = __expf(S[i][j] - newm);
                s4 += S[i][j];
            }
            #pragma unroll
            for (int off = 1; off < 16; off <<= 1)
                s4 += __shfl_xor(s4, off);
            l[i] = l[i] * alpha + s4;
            #pragma unroll
            for (int j = 0; j < 4; ++j) O[i][j] *= alpha;
        }

        __syncthreads();   // everyone done reading K before P overwrites
        #pragma unroll
        for (int i = 0; i < 4; ++i)
            #pragma unroll
            for (int j = 0; j < 4; ++j)
                KPs[ty * 4 + i][tx * 4 + j] = S[i][j];
        __syncthreads();

        // O += P V : rows ty*4.., d-cols tx*4..
        #pragma unroll
        for (int s = 0; s < 64; ++s) {
            float p[4], vv[4];
            #pragma unroll
            for (int i = 0; i < 4; ++i) p[i] = KPs[ty * 4 + i][s];
            #pragma unroll
            for (int j = 0; j < 4; ++j) vv[j] = Vs[s][tx * 4 + j];
            #pragma unroll
            for (int i = 0; i < 4; ++i)
                #pragma unroll
                for (int j = 0; j < 4; ++j)
                    O[i][j] += p[i] * vv[j];
        }
        __syncthreads();   // before next K/V load overwrites tiles
    }

    #pragma unroll
    for (int i = 0; i < 4; ++i) {
        float inv = 1.f / l[i];
        int t = q0 + ty * 4 + i;
        #pragma unroll
        for (int j = 0; j < 4; ++j)
            A[base + (size_t)t * D_DIM + tx * 4 + j] = O[i][j] * inv;
    }
}

// ---------------------------------------------------------------------------
// Output projection: out[m,e] = sum_k A[m,k]*gate[h(k)]*Wo[k,e] + bsum[e]
// A is [B,H,T,D] viewed as [M=B*T, K=H*D]; Wo is [H*D, E] contiguous.
// ---------------------------------------------------------------------------
__global__ __launch_bounds__(256) void out_gemm_kernel(
    const float* __restrict__ A, const float* __restrict__ Wo,
    const float* __restrict__ gate, const float* __restrict__ bsum,
    float* __restrict__ Out) {
    const int n0 = blockIdx.y * 64;
    const int m0 = blockIdx.x * 64;
    const int b = m0 / T_DIM;
    const int t0 = m0 % T_DIM;

    __shared__ float As[16][65];
    __shared__ float Ws2[16][64];

    const int tid = threadIdx.x;
    const int tx = tid % 16, ty = tid / 16;
    float acc[4][4] = {};

    for (int k0 = 0; k0 < H_DIM * D_DIM; k0 += 16) {
        const int h = k0 / D_DIM;
        const int d0 = k0 % D_DIM;
        const float g = gate[h];
        {
            int mm = tid / 4;
            int kk = (tid % 4) * 4;
            const float* src = A + ((size_t)(b * H_DIM + h) * T_DIM + t0 + mm) * D_DIM + d0 + kk;
            float4 v = *reinterpret_cast<const float4*>(src);
            As[kk + 0][mm] = v.x * g; As[kk + 1][mm] = v.y * g;
            As[kk + 2][mm] = v.z * g; As[kk + 3][mm] = v.w * g;
        }
        {
            int kk = tid / 16;
            int n = (tid % 16) * 4;
            const float4 v = *reinterpret_cast<const float4*>(
                Wo + (size_t)(k0 + kk) * E_DIM + n0 + n);
            *reinterpret_cast<float4*>(&Ws2[kk][n]) = v;
        }
        __syncthreads();
        #pragma unroll
        for (int kk = 0; kk < 16; ++kk) {
            float a[4], bb[4];
            #pragma unroll
            for (int i = 0; i < 4; ++i) a[i] = As[kk][ty * 4 + i];
            #pragma unroll
            for (int j = 0; j < 4; ++j) bb[j] = Ws2[kk][tx * 4 + j];
            #pragma unroll
            for (int i = 0; i < 4; ++i)
                #pragma unroll
                for (int j = 0; j < 4; ++j)
                    acc[i][j] += a[i] * bb[j];
        }
        __syncthreads();
    }

    float bj[4];
    #pragma unroll
    for (int j = 0; j < 4; ++j) bj[j] = bsum[n0 + tx * 4 + j];
    #pragma unroll
    for (int i = 0; i < 4; ++i) {
        int mrow = m0 + ty * 4 + i;
        #pragma unroll
        for (int j = 0; j < 4; ++j)
            Out[(size_t)mrow * E_DIM + n0 + tx * 4 + j] = acc[i][j] + bj[j];
    }
}

// ---------------------------------------------------------------------------
extern "C" void kernel_launch(void* const* d_in, const int* in_sizes, int n_in,
                              void* d_out, int out_size, void* d_ws, size_t ws_size,
                              hipStream_t stream) {
    const float* hs   = (const float*)d_in[0];
    const float* Wq   = (const float*)d_in[1];
    const float* bq   = (const float*)d_in[2];
    const float* Wk   = (const float*)d_in[3];
    const float* bk   = (const float*)d_in[4];
    const float* Wv   = (const float*)d_in[5];
    const float* bv   = (const float*)d_in[6];
    const float* Wo   = (const float*)d_in[7];
    const float* bo   = (const float*)d_in[8];
    const float* gate = (const float*)d_in[9];
    float* out = (float*)d_out;

    float* ws = (float*)d_ws;
    const size_t NQ = (size_t)B_DIM * H_DIM * T_DIM * D_DIM;  // 4M floats
    float* Qw   = ws;
    float* Kw   = ws + NQ;
    float* Vw   = ws + 2 * NQ;
    float* Aw   = ws + 3 * NQ;
    float* bsum = ws + 4 * NQ;

    bias_sum_kernel<<<dim3(4), dim3(256), 0, stream>>>(bo, gate, bsum);

    dim3 pgrid(B_DIM * T_DIM / 64, H_DIM);   // (64, 16)
    proj_gemm_kernel<<<pgrid, 256, 0, stream>>>(hs, Wq, bq, Qw);
    proj_gemm_kernel<<<pgrid, 256, 0, stream>>>(hs, Wk, bk, Kw);
    proj_gemm_kernel<<<pgrid, 256, 0, stream>>>(hs, Wv, bv, Vw);

    attn_kernel<<<dim3(T_DIM / 64, B_DIM * H_DIM), 256, 0, stream>>>(Qw, Kw, Vw, Aw);

    out_gemm_kernel<<<dim3(B_DIM * T_DIM / 64, E_DIM / 64), 256, 0, stream>>>(
        Aw, Wo, gate, bsum, out);
}

// Round 2
// 296.156 us; speedup vs baseline: 4.4710x; 4.4710x over previous
//
#include <hip/hip_runtime.h>
#include <math.h>

#define E_DIM 1024
#define H_DIM 16
#define D_DIM 64
#define B_DIM 2
#define T_DIM 2048
#define M_TOT (B_DIM * T_DIM)   // 4096

typedef __bf16 bf16_t;
typedef bf16_t bf16x8 __attribute__((ext_vector_type(8)));
typedef float f32x4 __attribute__((ext_vector_type(4)));

// ---------------------------------------------------------------------------
// Prep: cast hidden_states fp32 -> bf16
// ---------------------------------------------------------------------------
__global__ __launch_bounds__(256) void cast_x_kernel(const float* __restrict__ x,
                                                     bf16_t* __restrict__ xb) {
    size_t i = ((size_t)blockIdx.x * 256 + threadIdx.x) * 8;
    float4 a = *reinterpret_cast<const float4*>(x + i);
    float4 b = *reinterpret_cast<const float4*>(x + i + 4);
    bf16x8 o;
    o[0] = (bf16_t)a.x; o[1] = (bf16_t)a.y; o[2] = (bf16_t)a.z; o[3] = (bf16_t)a.w;
    o[4] = (bf16_t)b.x; o[5] = (bf16_t)b.y; o[6] = (bf16_t)b.z; o[7] = (bf16_t)b.w;
    *reinterpret_cast<bf16x8*>(xb + i) = o;
}

// ---------------------------------------------------------------------------
// Prep: transpose QKV weights [H][E][D] -> [H][D][E] bf16 (blockIdx.y picks q/k/v)
// ---------------------------------------------------------------------------
__global__ __launch_bounds__(256) void wqkv_t_kernel(
    const float* __restrict__ Wq, const float* __restrict__ Wk,
    const float* __restrict__ Wv, bf16_t* __restrict__ Wqt,
    bf16_t* __restrict__ Wkt, bf16_t* __restrict__ Wvt) {
    const float* W = blockIdx.y == 0 ? Wq : (blockIdx.y == 1 ? Wk : Wv);
    bf16_t* Wt = blockIdx.y == 0 ? Wqt : (blockIdx.y == 1 ? Wkt : Wvt);
    int t = blockIdx.x * 256 + threadIdx.x;    // [0, H*D*E)
    int h = t >> 16;                            // D*E = 65536
    int r = t & 65535;
    int d = r >> 10;
    int e = r & 1023;
    Wt[t] = (bf16_t)W[h * 65536 + e * 64 + d];
}

// ---------------------------------------------------------------------------
// Prep: Wgt[e][h*64+d] = Wo[h][d][e] * gate[h], bf16
// ---------------------------------------------------------------------------
__global__ __launch_bounds__(256) void wo_t_kernel(const float* __restrict__ Wo,
                                                   const float* __restrict__ gate,
                                                   bf16_t* __restrict__ Wgt) {
    int t = blockIdx.x * 256 + threadIdx.x;    // [0, E*H*D)
    int e = t >> 10;
    int c = t & 1023;
    Wgt[t] = (bf16_t)(Wo[c * 1024 + e] * gate[c >> 6]);
}

// ---------------------------------------------------------------------------
// Prep: bsum[e] = sum_h gate[h]*bo[h][e]  (fp32)
// ---------------------------------------------------------------------------
__global__ __launch_bounds__(256) void bias_sum_kernel(const float* __restrict__ bo,
                                                       const float* __restrict__ gate,
                                                       float* __restrict__ bsum) {
    int e = blockIdx.x * 256 + threadIdx.x;
    float s = 0.f;
    #pragma unroll
    for (int h = 0; h < H_DIM; ++h) s += gate[h] * bo[h * E_DIM + e];
    bsum[e] = s;
}

// ---------------------------------------------------------------------------
// QKV projection, bf16 MFMA. Block: 128(m) x 64(d), 4 waves (2x2), K=1024.
// z=0: Q (scaled by 0.125, layout [bh][t][d])
// z=1: K (layout [bh][t][d])
// z=2: V (layout [bh][d][t], transposed for PV B-operand)
// ---------------------------------------------------------------------------
__global__ __launch_bounds__(256) void proj_mfma_kernel(
    const bf16_t* __restrict__ Xb,
    const bf16_t* __restrict__ Wqt, const bf16_t* __restrict__ Wkt,
    const bf16_t* __restrict__ Wvt,
    const float* __restrict__ bqp, const float* __restrict__ bkp,
    const float* __restrict__ bvp,
    bf16_t* __restrict__ Qw, bf16_t* __restrict__ Kw, bf16_t* __restrict__ Vtw) {
    const int z = blockIdx.z;
    const bf16_t* Wt = z == 0 ? Wqt : (z == 1 ? Wkt : Wvt);
    const float* bias = z == 0 ? bqp : (z == 1 ? bkp : bvp);
    const float scale = (z == 0) ? 0.125f : 1.0f;
    const int h = blockIdx.y;
    const int m0 = blockIdx.x * 128;

    __shared__ bf16_t Xs[128][40];   // [m][k], pad 32->40
    __shared__ bf16_t Ws[64][40];    // [n=d][k]

    const int tid = threadIdx.x;
    const int lane = tid & 63;
    const int wid = tid >> 6;
    const int wr = wid >> 1, wc = wid & 1;
    const int lr = lane & 15, lg = lane >> 4;

    f32x4 acc[4][2] = {};
    const bf16_t* Wh = Wt + (size_t)h * D_DIM * E_DIM;

    for (int k0 = 0; k0 < E_DIM; k0 += 32) {
        {   // stage X tile: 128 rows x 32 k
            int row = tid >> 1;
            int off = (tid & 1) * 16;
            const bf16_t* src = Xb + (size_t)(m0 + row) * E_DIM + k0 + off;
            *reinterpret_cast<bf16x8*>(&Xs[row][off])     = *reinterpret_cast<const bf16x8*>(src);
            *reinterpret_cast<bf16x8*>(&Xs[row][off + 8]) = *reinterpret_cast<const bf16x8*>(src + 8);
        }
        {   // stage W tile: 64 rows (d) x 32 k
            int row = tid >> 2;
            int off = (tid & 3) * 8;
            const bf16_t* src = Wh + (size_t)row * E_DIM + k0 + off;
            *reinterpret_cast<bf16x8*>(&Ws[row][off]) = *reinterpret_cast<const bf16x8*>(src);
        }
        __syncthreads();
        bf16x8 a[4], bf[2];
        #pragma unroll
        for (int i = 0; i < 4; ++i)
            a[i] = *reinterpret_cast<const bf16x8*>(&Xs[wr * 64 + i * 16 + lr][lg * 8]);
        #pragma unroll
        for (int n = 0; n < 2; ++n)
            bf[n] = *reinterpret_cast<const bf16x8*>(&Ws[wc * 32 + n * 16 + lr][lg * 8]);
        #pragma unroll
        for (int i = 0; i < 4; ++i)
            #pragma unroll
            for (int n = 0; n < 2; ++n)
                acc[i][n] = __builtin_amdgcn_mfma_f32_16x16x32_bf16(a[i], bf[n], acc[i][n], 0, 0, 0);
        __syncthreads();
    }

    const int b_idx = m0 / T_DIM;
    const int t0 = m0 % T_DIM;
    float bj[2];
    #pragma unroll
    for (int n = 0; n < 2; ++n) bj[n] = bias[h * D_DIM + wc * 32 + n * 16 + lr];

    if (z != 2) {
        bf16_t* O = (z == 0 ? Qw : Kw) + (size_t)(b_idx * H_DIM + h) * T_DIM * D_DIM;
        #pragma unroll
        for (int i = 0; i < 4; ++i)
            #pragma unroll
            for (int n = 0; n < 2; ++n)
                #pragma unroll
                for (int r = 0; r < 4; ++r) {
                    int t = t0 + wr * 64 + i * 16 + lg * 4 + r;
                    int d = wc * 32 + n * 16 + lr;
                    O[(size_t)t * D_DIM + d] = (bf16_t)((acc[i][n][r] + bj[n]) * scale);
                }
    } else {
        bf16_t* O = Vtw + (size_t)(b_idx * H_DIM + h) * D_DIM * T_DIM;
        #pragma unroll
        for (int i = 0; i < 4; ++i)
            #pragma unroll
            for (int n = 0; n < 2; ++n) {
                int d = wc * 32 + n * 16 + lr;
                int tb = t0 + wr * 64 + i * 16 + lg * 4;
                bf16_t tmp[4];
                #pragma unroll
                for (int r = 0; r < 4; ++r) tmp[r] = (bf16_t)(acc[i][n][r] + bj[n]);
                *reinterpret_cast<uint2*>(&O[(size_t)d * T_DIM + tb]) =
                    *reinterpret_cast<uint2*>(tmp);
            }
    }
}

// ---------------------------------------------------------------------------
// Flash attention, bf16 MFMA. Block = 4 waves; each wave owns 16 q-rows.
// Q pre-scaled by 1/8. K: [bh][t][d]; V: [bh][d][t]. Out: Aw[b*T+t][h*64+d] bf16.
// ---------------------------------------------------------------------------
__global__ __launch_bounds__(256) void attn_mfma_kernel(
    const bf16_t* __restrict__ Q, const bf16_t* __restrict__ K,
    const bf16_t* __restrict__ Vt, bf16_t* __restrict__ Aw) {
    const int bh = blockIdx.y;
    const int b_idx = bh / H_DIM, h = bh % H_DIM;
    const int q0 = blockIdx.x * 64;
    const size_t base = (size_t)bh * T_DIM * D_DIM;

    __shared__ bf16_t Ks[64][72];      // [s][d], pad 64->72
    __shared__ bf16_t Vs[64][72];      // [d][s]
    __shared__ bf16_t Ps[4][16][72];   // per-wave P tile [qrow][s]

    const int tid = threadIdx.x;
    const int lane = tid & 63;
    const int wid = tid >> 6;
    const int lr = lane & 15, lg = lane >> 4;

    bf16x8 aq[2];
    #pragma unroll
    for (int kc = 0; kc < 2; ++kc)
        aq[kc] = *reinterpret_cast<const bf16x8*>(
            Q + base + (size_t)(q0 + wid * 16 + lr) * D_DIM + kc * 32 + lg * 8);

    float mrow[4], lrow[4];
    f32x4 o[4] = {};
    #pragma unroll
    for (int r = 0; r < 4; ++r) { mrow[r] = -INFINITY; lrow[r] = 0.f; }

    for (int s0 = 0; s0 < T_DIM; s0 += 64) {
        {   // stage K [64][64] and V [64][64]
            int row = tid >> 2;
            int off = (tid & 3) * 16;
            const bf16_t* ksrc = K + base + (size_t)(s0 + row) * D_DIM + off;
            *reinterpret_cast<bf16x8*>(&Ks[row][off])     = *reinterpret_cast<const bf16x8*>(ksrc);
            *reinterpret_cast<bf16x8*>(&Ks[row][off + 8]) = *reinterpret_cast<const bf16x8*>(ksrc + 8);
            const bf16_t* vsrc = Vt + base + (size_t)row * T_DIM + s0 + off;
            *reinterpret_cast<bf16x8*>(&Vs[row][off])     = *reinterpret_cast<const bf16x8*>(vsrc);
            *reinterpret_cast<bf16x8*>(&Vs[row][off + 8]) = *reinterpret_cast<const bf16x8*>(vsrc + 8);
        }
        __syncthreads();

        // S = (Q/8) K^T  -> lane holds S[row=lg*4+r][col=ns*16+lr]
        f32x4 s[4] = {};
        #pragma unroll
        for (int ns = 0; ns < 4; ++ns)
            #pragma unroll
            for (int kc = 0; kc < 2; ++kc) {
                bf16x8 bk = *reinterpret_cast<const bf16x8*>(&Ks[ns * 16 + lr][kc * 32 + lg * 8]);
                s[ns] = __builtin_amdgcn_mfma_f32_16x16x32_bf16(aq[kc], bk, s[ns], 0, 0, 0);
            }

        // online softmax per q-row (16 lanes of a lg-group share a row set)
        #pragma unroll
        for (int r = 0; r < 4; ++r) {
            float mx = fmaxf(fmaxf(s[0][r], s[1][r]), fmaxf(s[2][r], s[3][r]));
            mx = fmaxf(mx, __shfl_xor(mx, 1));
            mx = fmaxf(mx, __shfl_xor(mx, 2));
            mx = fmaxf(mx, __shfl_xor(mx, 4));
            mx = fmaxf(mx, __shfl_xor(mx, 8));
            float newm = fmaxf(mrow[r], mx);
            float alpha = __expf(mrow[r] - newm);
            mrow[r] = newm;
            float rs = 0.f;
            #pragma unroll
            for (int ns = 0; ns < 4; ++ns) {
                float p = __expf(s[ns][r] - newm);
                rs += p;
                Ps[wid][lg * 4 + r][ns * 16 + lr] = (bf16_t)p;
            }
            rs += __shfl_xor(rs, 1);
            rs += __shfl_xor(rs, 2);
            rs += __shfl_xor(rs, 4);
            rs += __shfl_xor(rs, 8);
            lrow[r] = lrow[r] * alpha + rs;
            #pragma unroll
            for (int nd = 0; nd < 4; ++nd) o[nd][r] *= alpha;
        }

        // O += P V   (A=P from wave-local LDS, B=V^T tile)
        #pragma unroll
        for (int sc = 0; sc < 2; ++sc) {
            bf16x8 ap = *reinterpret_cast<const bf16x8*>(&Ps[wid][lr][sc * 32 + lg * 8]);
            #pragma unroll
            for (int nd = 0; nd < 4; ++nd) {
                bf16x8 bv8 = *reinterpret_cast<const bf16x8*>(&Vs[nd * 16 + lr][sc * 32 + lg * 8]);
                o[nd] = __builtin_amdgcn_mfma_f32_16x16x32_bf16(ap, bv8, o[nd], 0, 0, 0);
            }
        }
        __syncthreads();
    }

    #pragma unroll
    for (int r = 0; r < 4; ++r) {
        float inv = 1.f / lrow[r];
        int t = q0 + wid * 16 + lg * 4 + r;
        size_t rowbase = ((size_t)b_idx * T_DIM + t) * E_DIM + h * D_DIM;
        #pragma unroll
        for (int nd = 0; nd < 4; ++nd)
            Aw[rowbase + nd * 16 + lr] = (bf16_t)(o[nd][r] * inv);
    }
}

// ---------------------------------------------------------------------------
// Output projection, bf16 MFMA: out[m][e] = sum_k Aw[m][k]*Wgt[e][k] + bsum[e]
// Block 128(m) x 64(e), K = 1024 (= H*D). fp32 output.
// ---------------------------------------------------------------------------
__global__ __launch_bounds__(256) void out_mfma_kernel(
    const bf16_t* __restrict__ Aw, const bf16_t* __restrict__ Wgt,
    const float* __restrict__ bsum, float* __restrict__ out) {
    const int m0 = blockIdx.x * 128;
    const int e0 = blockIdx.y * 64;

    __shared__ bf16_t As[128][40];
    __shared__ bf16_t Ws[64][40];

    const int tid = threadIdx.x;
    const int lane = tid & 63;
    const int wid = tid >> 6;
    const int wr = wid >> 1, wc = wid & 1;
    const int lr = lane & 15, lg = lane >> 4;

    f32x4 acc[4][2] = {};

    for (int k0 = 0; k0 < E_DIM; k0 += 32) {
        {
            int row = tid >> 1;
            int off = (tid & 1) * 16;
            const bf16_t* src = Aw + (size_t)(m0 + row) * E_DIM + k0 + off;
            *reinterpret_cast<bf16x8*>(&As[row][off])     = *reinterpret_cast<const bf16x8*>(src);
            *reinterpret_cast<bf16x8*>(&As[row][off + 8]) = *reinterpret_cast<const bf16x8*>(src + 8);
        }
        {
            int row = tid >> 2;
            int off = (tid & 3) * 8;
            const bf16_t* src = Wgt + (size_t)(e0 + row) * E_DIM + k0 + off;
            *reinterpret_cast<bf16x8*>(&Ws[row][off]) = *reinterpret_cast<const bf16x8*>(src);
        }
        __syncthreads();
        bf16x8 a[4], bf[2];
        #pragma unroll
        for (int i = 0; i < 4; ++i)
            a[i] = *reinterpret_cast<const bf16x8*>(&As[wr * 64 + i * 16 + lr][lg * 8]);
        #pragma unroll
        for (int n = 0; n < 2; ++n)
            bf[n] = *reinterpret_cast<const bf16x8*>(&Ws[wc * 32 + n * 16 + lr][lg * 8]);
        #pragma unroll
        for (int i = 0; i < 4; ++i)
            #pragma unroll
            for (int n = 0; n < 2; ++n)
                acc[i][n] = __builtin_amdgcn_mfma_f32_16x16x32_bf16(a[i], bf[n], acc[i][n], 0, 0, 0);
        __syncthreads();
    }

    #pragma unroll
    for (int i = 0; i < 4; ++i)
        #pragma unroll
        for (int n = 0; n < 2; ++n) {
            int e = e0 + wc * 32 + n * 16 + lr;
            float be = bsum[e];
            #pragma unroll
            for (int r = 0; r < 4; ++r) {
                int mrow = m0 + wr * 64 + i * 16 + lg * 4 + r;
                out[(size_t)mrow * E_DIM + e] = acc[i][n][r] + be;
            }
        }
}

// ---------------------------------------------------------------------------
extern "C" void kernel_launch(void* const* d_in, const int* in_sizes, int n_in,
                              void* d_out, int out_size, void* d_ws, size_t ws_size,
                              hipStream_t stream) {
    const float* hs   = (const float*)d_in[0];
    const float* Wq   = (const float*)d_in[1];
    const float* bq   = (const float*)d_in[2];
    const float* Wk   = (const float*)d_in[3];
    const float* bk   = (const float*)d_in[4];
    const float* Wv   = (const float*)d_in[5];
    const float* bv   = (const float*)d_in[6];
    const float* Wo   = (const float*)d_in[7];
    const float* bo   = (const float*)d_in[8];
    const float* gate = (const float*)d_in[9];
    float* out = (float*)d_out;

    const size_t NX  = (size_t)M_TOT * E_DIM;          // 4096*1024
    const size_t NW  = (size_t)H_DIM * D_DIM * E_DIM;  // 1M
    bf16_t* p = (bf16_t*)d_ws;
    bf16_t* Xb  = p; p += NX;
    bf16_t* Wqt = p; p += NW;
    bf16_t* Wkt = p; p += NW;
    bf16_t* Wvt = p; p += NW;
    bf16_t* Wgt = p; p += NW;
    bf16_t* Qw  = p; p += NX;
    bf16_t* Kw  = p; p += NX;
    bf16_t* Vtw = p; p += NX;
    bf16_t* Aw  = p; p += NX;
    float*  bsum = (float*)p;

    cast_x_kernel<<<dim3(NX / (256 * 8)), 256, 0, stream>>>(hs, Xb);
    wqkv_t_kernel<<<dim3(NW / 256, 3), 256, 0, stream>>>(Wq, Wk, Wv, Wqt, Wkt, Wvt);
    wo_t_kernel<<<dim3(NW / 256), 256, 0, stream>>>(Wo, gate, Wgt);
    bias_sum_kernel<<<dim3(E_DIM / 256), 256, 0, stream>>>(bo, gate, bsum);

    proj_mfma_kernel<<<dim3(M_TOT / 128, H_DIM, 3), 256, 0, stream>>>(
        Xb, Wqt, Wkt, Wvt, bq, bk, bv, Qw, Kw, Vtw);

    attn_mfma_kernel<<<dim3(T_DIM / 64, B_DIM * H_DIM), 256, 0, stream>>>(Qw, Kw, Vtw, Aw);

    out_mfma_kernel<<<dim3(M_TOT / 128, E_DIM / 64), 256, 0, stream>>>(Aw, Wgt, bsum, out);
}

// Round 3
// 215.899 us; speedup vs baseline: 6.1331x; 1.3717x over previous
//
#include <hip/hip_runtime.h>
#include <math.h>

#define E_DIM 1024
#define H_DIM 16
#define D_DIM 64
#define B_DIM 2
#define T_DIM 2048
#define M_TOT (B_DIM * T_DIM)   // 4096

typedef __bf16 bf16_t;
typedef bf16_t bf16x4 __attribute__((ext_vector_type(4)));
typedef bf16_t bf16x8 __attribute__((ext_vector_type(8)));
typedef float f32x4 __attribute__((ext_vector_type(4)));

__device__ __forceinline__ void load_lds16(const void* g, void* l) {
    __builtin_amdgcn_global_load_lds(
        (const __attribute__((address_space(1))) unsigned int*)g,
        (__attribute__((address_space(3))) unsigned int*)l, 16, 0, 0);
}

// ---------------------------------------------------------------------------
// Prep: cast hidden_states fp32 -> bf16
// ---------------------------------------------------------------------------
__global__ __launch_bounds__(256) void cast_x_kernel(const float* __restrict__ x,
                                                     bf16_t* __restrict__ xb) {
    size_t i = ((size_t)blockIdx.x * 256 + threadIdx.x) * 8;
    float4 a = *reinterpret_cast<const float4*>(x + i);
    float4 b = *reinterpret_cast<const float4*>(x + i + 4);
    bf16x8 o;
    o[0] = (bf16_t)a.x; o[1] = (bf16_t)a.y; o[2] = (bf16_t)a.z; o[3] = (bf16_t)a.w;
    o[4] = (bf16_t)b.x; o[5] = (bf16_t)b.y; o[6] = (bf16_t)b.z; o[7] = (bf16_t)b.w;
    *reinterpret_cast<bf16x8*>(xb + i) = o;
}

// ---------------------------------------------------------------------------
// Prep: Wcat[(z*16+h)*64 + d][e] = Wz[h][e][d], bf16. Tiled coalesced transpose.
// grid (E/64, H, 3), 256 thr.
// ---------------------------------------------------------------------------
__global__ __launch_bounds__(256) void wqkv_t_kernel(
    const float* __restrict__ Wq, const float* __restrict__ Wk,
    const float* __restrict__ Wv, bf16_t* __restrict__ Wcat) {
    const int et = blockIdx.x, h = blockIdx.y, z = blockIdx.z;
    const float* W = z == 0 ? Wq : (z == 1 ? Wk : Wv);
    __shared__ float Tt[64][65];
    const int tid = threadIdx.x;
    const int r = tid >> 2, c4 = (tid & 3) * 16;
    const float* src = W + (size_t)h * 65536 + (size_t)(et * 64 + r) * 64 + c4;
    #pragma unroll
    for (int k = 0; k < 16; k += 4) {
        float4 v = *reinterpret_cast<const float4*>(src + k);
        Tt[r][c4 + k + 0] = v.x; Tt[r][c4 + k + 1] = v.y;
        Tt[r][c4 + k + 2] = v.z; Tt[r][c4 + k + 3] = v.w;
    }
    __syncthreads();
    bf16x8 o0, o1;
    #pragma unroll
    for (int k = 0; k < 8; ++k) o0[k] = (bf16_t)Tt[c4 + k][r];
    #pragma unroll
    for (int k = 0; k < 8; ++k) o1[k] = (bf16_t)Tt[c4 + 8 + k][r];
    bf16_t* dst = Wcat + ((size_t)(z * 16 + h) * 64 + r) * 1024 + et * 64 + c4;
    *reinterpret_cast<bf16x8*>(dst) = o0;
    *reinterpret_cast<bf16x8*>(dst + 8) = o1;
}

// ---------------------------------------------------------------------------
// Prep: Wgt[e][h*64+d] = Wo[h][d][e]*gate[h], bf16. grid (E/64, H).
// ---------------------------------------------------------------------------
__global__ __launch_bounds__(256) void wo_t_kernel(const float* __restrict__ Wo,
                                                   const float* __restrict__ gate,
                                                   bf16_t* __restrict__ Wgt) {
    const int et = blockIdx.x, h = blockIdx.y;
    const float g = gate[h];
    __shared__ float Tt[64][65];
    const int tid = threadIdx.x;
    const int r = tid >> 2, c4 = (tid & 3) * 16;
    const float* src = Wo + (size_t)h * 65536 + (size_t)r * 1024 + et * 64 + c4;
    #pragma unroll
    for (int k = 0; k < 16; k += 4) {
        float4 v = *reinterpret_cast<const float4*>(src + k);
        Tt[r][c4 + k + 0] = v.x * g; Tt[r][c4 + k + 1] = v.y * g;
        Tt[r][c4 + k + 2] = v.z * g; Tt[r][c4 + k + 3] = v.w * g;
    }
    __syncthreads();
    bf16x8 o0, o1;
    #pragma unroll
    for (int k = 0; k < 8; ++k) o0[k] = (bf16_t)Tt[c4 + k][r];
    #pragma unroll
    for (int k = 0; k < 8; ++k) o1[k] = (bf16_t)Tt[c4 + 8 + k][r];
    bf16_t* dst = Wgt + (size_t)(et * 64 + r) * 1024 + h * 64 + c4;
    *reinterpret_cast<bf16x8*>(dst) = o0;
    *reinterpret_cast<bf16x8*>(dst + 8) = o1;
}

// ---------------------------------------------------------------------------
// Prep: bsum[e] = sum_h gate[h]*bo[h][e]
// ---------------------------------------------------------------------------
__global__ __launch_bounds__(256) void bias_sum_kernel(const float* __restrict__ bo,
                                                       const float* __restrict__ gate,
                                                       float* __restrict__ bsum) {
    int e = blockIdx.x * 256 + threadIdx.x;
    float s = 0.f;
    #pragma unroll
    for (int h = 0; h < H_DIM; ++h) s += gate[h] * bo[h * E_DIM + e];
    bsum[e] = s;
}

// ---------------------------------------------------------------------------
// Fused QKV GEMM: [4096 x 3072 x 1024], 128x128 tile, BK=32, global_load_lds.
// n = z*1024 + h*64 + d. Epilogue: +bias, Q scaled 0.125, V written transposed.
// ---------------------------------------------------------------------------
__global__ __launch_bounds__(256) void qkv_gemm_kernel(
    const bf16_t* __restrict__ Xb, const bf16_t* __restrict__ Wcat,
    const float* __restrict__ bqp, const float* __restrict__ bkp,
    const float* __restrict__ bvp,
    bf16_t* __restrict__ Qw, bf16_t* __restrict__ Kw, bf16_t* __restrict__ Vtw) {
    const int p = blockIdx.x;                    // 768 blocks, 768%8==0
    const int l = (p & 7) * 96 + (p >> 3);       // bijective XCD swizzle
    const int mx = l & 31, ny = l >> 5;
    const int m0 = mx * 128, n0 = ny * 128;

    __shared__ bf16_t As[128][32];
    __shared__ bf16_t Bs[128][32];

    const int tid = threadIdx.x;
    const int lane = tid & 63, wid = tid >> 6;
    const int wr = wid >> 1, wc = wid & 1;
    const int lr = lane & 15, lg = lane >> 4;
    const int srow = lane >> 2, scol = (lane & 3) * 8;

    f32x4 acc[4][4] = {};

    for (int k0 = 0; k0 < E_DIM; k0 += 32) {
        #pragma unroll
        for (int j = 0; j < 2; ++j) {
            load_lds16(Xb + (size_t)(m0 + wid * 32 + j * 16 + srow) * E_DIM + k0 + scol,
                       (char*)&As[0][0] + wid * 2048 + j * 1024);
            load_lds16(Wcat + (size_t)(n0 + wid * 32 + j * 16 + srow) * E_DIM + k0 + scol,
                       (char*)&Bs[0][0] + wid * 2048 + j * 1024);
        }
        __syncthreads();
        bf16x8 a[4], b[4];
        #pragma unroll
        for (int i = 0; i < 4; ++i)
            a[i] = *reinterpret_cast<const bf16x8*>(&As[wr * 64 + i * 16 + lr][lg * 8]);
        #pragma unroll
        for (int j = 0; j < 4; ++j)
            b[j] = *reinterpret_cast<const bf16x8*>(&Bs[wc * 64 + j * 16 + lr][lg * 8]);
        __builtin_amdgcn_s_setprio(1);
        #pragma unroll
        for (int i = 0; i < 4; ++i)
            #pragma unroll
            for (int j = 0; j < 4; ++j)
                acc[i][j] = __builtin_amdgcn_mfma_f32_16x16x32_bf16(a[i], b[j], acc[i][j], 0, 0, 0);
        __builtin_amdgcn_s_setprio(0);
        __syncthreads();
    }

    const int z = n0 >> 10;                      // uniform per block
    const float scale = (z == 0) ? 0.125f : 1.0f;
    const float* bias = z == 0 ? bqp : (z == 1 ? bkp : bvp);
    const int b_idx = m0 >> 11;
    const int t00 = m0 & (T_DIM - 1);

    #pragma unroll
    for (int j = 0; j < 4; ++j) {
        const int n = n0 + wc * 64 + j * 16 + lr;
        const int h = (n >> 6) & 15;
        const int d = n & 63;
        const float bval = bias[n & 1023];
        if (z != 2) {
            bf16_t* O = (z == 0 ? Qw : Kw) + (size_t)(b_idx * H_DIM + h) * T_DIM * 64;
            #pragma unroll
            for (int i = 0; i < 4; ++i)
                #pragma unroll
                for (int r = 0; r < 4; ++r) {
                    int t = t00 + wr * 64 + i * 16 + lg * 4 + r;
                    O[(size_t)t * 64 + d] = (bf16_t)((acc[i][j][r] + bval) * scale);
                }
        } else {
            bf16_t* O = Vtw + (size_t)(b_idx * H_DIM + h) * 64 * T_DIM + (size_t)d * T_DIM;
            #pragma unroll
            for (int i = 0; i < 4; ++i) {
                int t = t00 + wr * 64 + i * 16 + lg * 4;
                bf16x4 t4;
                #pragma unroll
                for (int r = 0; r < 4; ++r) t4[r] = (bf16_t)(acc[i][j][r] + bval);
                *reinterpret_cast<bf16x4*>(&O[t]) = t4;
            }
        }
    }
}

// ---------------------------------------------------------------------------
// Flash attention: 8 waves x 16 q-rows (QBLK=128), KVBLK=128, swapped QK^T
// so each lane owns a full P row (q = lane&15). Defer-max rescale (THR=8).
// Q pre-scaled by 0.125. K:[bh][t][d], V:[bh][d][t]. Out: Aw[b*T+t][h*64+d].
// ---------------------------------------------------------------------------
__global__ __launch_bounds__(512, 4) void attn_mfma_kernel(
    const bf16_t* __restrict__ Q, const bf16_t* __restrict__ K,
    const bf16_t* __restrict__ Vt, bf16_t* __restrict__ Aw) {
    const int p = blockIdx.x;                    // 512 blocks
    const int l = (p & 7) * 64 + (p >> 3);       // XCD swizzle: 4 heads/XCD chunk
    const int qx = l & 15, bh = l >> 4;
    const int b_idx = bh >> 4, h = bh & 15;
    const int q0 = qx * 128;
    const size_t base = (size_t)bh * T_DIM * 64;

    __shared__ bf16_t Ks[128][72];
    __shared__ bf16_t Vs[64][136];
    __shared__ bf16_t Ps[8][16][136];

    const int tid = threadIdx.x;
    const int lane = tid & 63;
    const int wid = tid >> 6;                    // 0..7
    const int lr = lane & 15, lg = lane >> 4;

    // Q fragments (B-operand): lane holds Q[q0+wid*16+lr][kc*32+lg*8 ..+8]
    bf16x8 bq[2];
    #pragma unroll
    for (int kc = 0; kc < 2; ++kc)
        bq[kc] = *reinterpret_cast<const bf16x8*>(
            Q + base + (size_t)(q0 + wid * 16 + lr) * 64 + kc * 32 + lg * 8);

    float mreg = -INFINITY, lrow = 0.f;
    f32x4 o[4] = {};

    for (int s0 = 0; s0 < T_DIM; s0 += 128) {
        {   // stage K (128x64) and V (64x128), coalesced, reg-staged (padded LDS)
            const int kr = tid >> 2, kc = (tid & 3) * 16;
            const bf16_t* ksrc = K + base + (size_t)(s0 + kr) * 64 + kc;
            *reinterpret_cast<bf16x8*>(&Ks[kr][kc])     = *reinterpret_cast<const bf16x8*>(ksrc);
            *reinterpret_cast<bf16x8*>(&Ks[kr][kc + 8]) = *reinterpret_cast<const bf16x8*>(ksrc + 8);
            const int vr = tid >> 3, vc = (tid & 7) * 16;
            const bf16_t* vsrc = Vt + base + (size_t)vr * T_DIM + s0 + vc;
            *reinterpret_cast<bf16x8*>(&Vs[vr][vc])     = *reinterpret_cast<const bf16x8*>(vsrc);
            *reinterpret_cast<bf16x8*>(&Vs[vr][vc + 8]) = *reinterpret_cast<const bf16x8*>(vsrc + 8);
        }
        __syncthreads();

        // S^T = mfma(K, Q): lane -> q = lr, s-idx = kb*16 + lg*4 + r
        f32x4 s[8] = {};
        __builtin_amdgcn_s_setprio(1);
        #pragma unroll
        for (int kb = 0; kb < 8; ++kb)
            #pragma unroll
            for (int kc = 0; kc < 2; ++kc) {
                bf16x8 ak = *reinterpret_cast<const bf16x8*>(&Ks[kb * 16 + lr][kc * 32 + lg * 8]);
                s[kb] = __builtin_amdgcn_mfma_f32_16x16x32_bf16(ak, bq[kc], s[kb], 0, 0, 0);
            }
        __builtin_amdgcn_s_setprio(0);

        // row max over the lane's 32 values, then across the 4 lg-groups
        float pmax = -INFINITY;
        #pragma unroll
        for (int kb = 0; kb < 8; ++kb) {
            float m01 = fmaxf(s[kb][0], s[kb][1]);
            float m23 = fmaxf(s[kb][2], s[kb][3]);
            pmax = fmaxf(pmax, fmaxf(m01, m23));
        }
        pmax = fmaxf(pmax, __shfl_xor(pmax, 16));
        pmax = fmaxf(pmax, __shfl_xor(pmax, 32));

        if (__any(pmax > mreg + 8.f)) {          // defer-max: rescale rarely
            float newm = fmaxf(mreg, pmax);
            float alpha = __expf(mreg - newm);
            mreg = newm;
            lrow *= alpha;
            #pragma unroll
            for (int r = 0; r < 4; ++r) {
                float ar = __shfl(alpha, lg * 4 + r);   // alpha of o's q-row
                o[0][r] *= ar; o[1][r] *= ar; o[2][r] *= ar; o[3][r] *= ar;
            }
        }

        // p = exp(s - m); accumulate row sum; pack to wave-local LDS
        float rs = 0.f;
        #pragma unroll
        for (int kb = 0; kb < 8; ++kb) {
            bf16x4 t4;
            #pragma unroll
            for (int r = 0; r < 4; ++r) {
                float pv = __expf(s[kb][r] - mreg);
                rs += pv;
                t4[r] = (bf16_t)pv;
            }
            *reinterpret_cast<bf16x4*>(&Ps[wid][lr][kb * 16 + lg * 4]) = t4;
        }
        rs += __shfl_xor(rs, 16);
        rs += __shfl_xor(rs, 32);
        lrow += rs;

        asm volatile("s_waitcnt lgkmcnt(0)" ::: "memory");

        // O += P V  (A = P wave-local, B = V^T tile)
        __builtin_amdgcn_s_setprio(1);
        #pragma unroll
        for (int sc = 0; sc < 4; ++sc) {
            bf16x8 ap = *reinterpret_cast<const bf16x8*>(&Ps[wid][lr][sc * 32 + lg * 8]);
            #pragma unroll
            for (int nd = 0; nd < 4; ++nd) {
                bf16x8 bv = *reinterpret_cast<const bf16x8*>(&Vs[nd * 16 + lr][sc * 32 + lg * 8]);
                o[nd] = __builtin_amdgcn_mfma_f32_16x16x32_bf16(ap, bv, o[nd], 0, 0, 0);
            }
        }
        __builtin_amdgcn_s_setprio(0);
        __syncthreads();
    }

    // epilogue: normalize by row-sum (fetch l for o's q-row via shfl)
    #pragma unroll
    for (int r = 0; r < 4; ++r) {
        float lsum = __shfl(lrow, lg * 4 + r);
        float linv = 1.f / lsum;
        int t = q0 + wid * 16 + lg * 4 + r;
        size_t rowbase = ((size_t)b_idx * T_DIM + t) * E_DIM + h * 64;
        #pragma unroll
        for (int nd = 0; nd < 4; ++nd)
            Aw[rowbase + nd * 16 + lr] = (bf16_t)(o[nd][r] * linv);
    }
}

// ---------------------------------------------------------------------------
// Output GEMM: [4096 x 1024 x 1024], 128x128 tile, BK=32. out fp32 + bsum.
// ---------------------------------------------------------------------------
__global__ __launch_bounds__(256) void out_gemm_kernel(
    const bf16_t* __restrict__ Aw, const bf16_t* __restrict__ Wgt,
    const float* __restrict__ bsum, float* __restrict__ out) {
    const int p = blockIdx.x;                    // 256 blocks
    const int l = (p & 7) * 32 + (p >> 3);
    const int mx = l & 31, ny = l >> 5;
    const int m0 = mx * 128, n0 = ny * 128;

    __shared__ bf16_t As[128][32];
    __shared__ bf16_t Bs[128][32];

    const int tid = threadIdx.x;
    const int lane = tid & 63, wid = tid >> 6;
    const int wr = wid >> 1, wc = wid & 1;
    const int lr = lane & 15, lg = lane >> 4;
    const int srow = lane >> 2, scol = (lane & 3) * 8;

    f32x4 acc[4][4] = {};

    for (int k0 = 0; k0 < E_DIM; k0 += 32) {
        #pragma unroll
        for (int j = 0; j < 2; ++j) {
            load_lds16(Aw + (size_t)(m0 + wid * 32 + j * 16 + srow) * E_DIM + k0 + scol,
                       (char*)&As[0][0] + wid * 2048 + j * 1024);
            load_lds16(Wgt + (size_t)(n0 + wid * 32 + j * 16 + srow) * E_DIM + k0 + scol,
                       (char*)&Bs[0][0] + wid * 2048 + j * 1024);
        }
        __syncthreads();
        bf16x8 a[4], b[4];
        #pragma unroll
        for (int i = 0; i < 4; ++i)
            a[i] = *reinterpret_cast<const bf16x8*>(&As[wr * 64 + i * 16 + lr][lg * 8]);
        #pragma unroll
        for (int j = 0; j < 4; ++j)
            b[j] = *reinterpret_cast<const bf16x8*>(&Bs[wc * 64 + j * 16 + lr][lg * 8]);
        __builtin_amdgcn_s_setprio(1);
        #pragma unroll
        for (int i = 0; i < 4; ++i)
            #pragma unroll
            for (int j = 0; j < 4; ++j)
                acc[i][j] = __builtin_amdgcn_mfma_f32_16x16x32_bf16(a[i], b[j], acc[i][j], 0, 0, 0);
        __builtin_amdgcn_s_setprio(0);
        __syncthreads();
    }

    #pragma unroll
    for (int j = 0; j < 4; ++j) {
        const int e = n0 + wc * 64 + j * 16 + lr;
        const float be = bsum[e];
        #pragma unroll
        for (int i = 0; i < 4; ++i)
            #pragma unroll
            for (int r = 0; r < 4; ++r) {
                int m = m0 + wr * 64 + i * 16 + lg * 4 + r;
                out[(size_t)m * E_DIM + e] = acc[i][j][r] + be;
            }
    }
}

// ---------------------------------------------------------------------------
extern "C" void kernel_launch(void* const* d_in, const int* in_sizes, int n_in,
                              void* d_out, int out_size, void* d_ws, size_t ws_size,
                              hipStream_t stream) {
    const float* hs   = (const float*)d_in[0];
    const float* Wq   = (const float*)d_in[1];
    const float* bq   = (const float*)d_in[2];
    const float* Wk   = (const float*)d_in[3];
    const float* bk   = (const float*)d_in[4];
    const float* Wv   = (const float*)d_in[5];
    const float* bv   = (const float*)d_in[6];
    const float* Wo   = (const float*)d_in[7];
    const float* bo   = (const float*)d_in[8];
    const float* gate = (const float*)d_in[9];
    float* out = (float*)d_out;

    const size_t NX = (size_t)M_TOT * E_DIM;           // 4M elems
    const size_t NW = (size_t)H_DIM * D_DIM * E_DIM;   // 1M elems
    bf16_t* p = (bf16_t*)d_ws;
    bf16_t* Xb   = p; p += NX;
    bf16_t* Wcat = p; p += 3 * NW;
    bf16_t* Wgt  = p; p += NW;
    bf16_t* Qw   = p; p += NX;
    bf16_t* Kw   = p; p += NX;
    bf16_t* Vtw  = p; p += NX;
    bf16_t* Aw   = p; p += NX;
    float*  bsum = (float*)p;

    cast_x_kernel<<<dim3(NX / 2048), 256, 0, stream>>>(hs, Xb);
    wqkv_t_kernel<<<dim3(16, 16, 3), 256, 0, stream>>>(Wq, Wk, Wv, Wcat);
    wo_t_kernel<<<dim3(16, 16), 256, 0, stream>>>(Wo, gate, Wgt);
    bias_sum_kernel<<<dim3(4), 256, 0, stream>>>(bo, gate, bsum);

    qkv_gemm_kernel<<<dim3(768), 256, 0, stream>>>(Xb, Wcat, bq, bk, bv, Qw, Kw, Vtw);

    attn_mfma_kernel<<<dim3(512), 512, 0, stream>>>(Qw, Kw, Vtw, Aw);

    out_gemm_kernel<<<dim3(256), 256, 0, stream>>>(Aw, Wgt, bsum, out);
}